// Round 5
// baseline (2914.888 us; speedup 1.0000x reference)
//
#include <hip/hip_runtime.h>
#include <stdint.h>

#define DHID 64      // hidden dim, fixed by problem
#define G_BLOCKS 512 // blocks in phase-A scatter/hist
#define RSH 7        // rows per bucket = 128
#define RPB 128
#define BMAX 1024    // max buckets (n <= 131072)
#define CSH 10       // col-group width = 1024 cols (256 KB of x)
#define CGMAX 128    // max col groups (n <= 131072)

static inline size_t align256(size_t x) { return (x + 255) & ~(size_t)255; }

// ---------------- generic helpers ----------------

__global__ void zero_f32(float* __restrict__ p, size_t n) {
  size_t i = (size_t)blockIdx.x * blockDim.x + threadIdx.x;
  if (i < n) p[i] = 0.f;
}

// ---------------- phase A: bucket partition (bucket = row >> RSH) --------------

__global__ void a1_hist_k(const int* __restrict__ row, int* __restrict__ histGB,
                          int nnz, int B, int chunk) {
  __shared__ int h[BMAX];
  for (int i = threadIdx.x; i < B; i += blockDim.x) h[i] = 0;
  __syncthreads();
  int g = blockIdx.x;
  int s = g * chunk, e = min(nnz, s + chunk);
  for (int j = s + threadIdx.x; j < e; j += blockDim.x)
    atomicAdd(&h[row[j] >> RSH], 1);
  __syncthreads();
  for (int i = threadIdx.x; i < B; i += blockDim.x)
    histGB[(size_t)i * G_BLOCKS + g] = h[i];
}

// exclusive scan across G_BLOCKS=512 values per bucket; 256 threads, 2 elems each
__global__ void scan_gb_k(const int* __restrict__ histGB, int* __restrict__ offGB,
                          int* __restrict__ btot, int B) {
  __shared__ int wsum[4];
  int b = blockIdx.x, t = threadIdx.x, lane = t & 63, w = t >> 6;
  int v0 = histGB[(size_t)b * G_BLOCKS + 2 * t];
  int v1 = histGB[(size_t)b * G_BLOCKS + 2 * t + 1];
  int ps = v0 + v1, incl = ps;
#pragma unroll
  for (int off = 1; off < 64; off <<= 1) {
    int u = __shfl_up(incl, off);
    if (lane >= off) incl += u;
  }
  if (lane == 63) wsum[w] = incl;
  __syncthreads();
  int woff = 0;
  for (int w2 = 0; w2 < w; ++w2) woff += wsum[w2];
  int ex = woff + incl - ps;
  offGB[(size_t)b * G_BLOCKS + 2 * t] = ex;
  offGB[(size_t)b * G_BLOCKS + 2 * t + 1] = ex + v0;
  if (t == 0) btot[b] = wsum[0] + wsum[1] + wsum[2] + wsum[3];
}

// exclusive scan of up to 1024 bucket totals -> base[0..B]. one block, 256 thr x4.
__global__ void scan_b_k(const int* __restrict__ btot, int* __restrict__ base, int B) {
  __shared__ int wsum[4];
  int t = threadIdx.x, lane = t & 63, w = t >> 6;
  int v[4], ps = 0;
#pragma unroll
  for (int i = 0; i < 4; ++i) {
    int idx = 4 * t + i;
    v[i] = (idx < B) ? btot[idx] : 0;
    ps += v[i];
  }
  int incl = ps;
#pragma unroll
  for (int off = 1; off < 64; off <<= 1) {
    int u = __shfl_up(incl, off);
    if (lane >= off) incl += u;
  }
  if (lane == 63) wsum[w] = incl;
  __syncthreads();
  int woff = 0;
  for (int w2 = 0; w2 < w; ++w2) woff += wsum[w2];
  int ex = woff + incl - ps;
#pragma unroll
  for (int i = 0; i < 4; ++i) {
    int idx = 4 * t + i;
    if (idx <= B) base[idx] = ex;
    ex += v[i];
  }
}

// scatter into bucket regions; each block writes only its private quota window.
// payload packs row-low-7 into bits 24..31 of the col word (col < 2^24).
__global__ void a2_scatter_k(const int* __restrict__ row, const int* __restrict__ col,
                             const float* __restrict__ val, const int* __restrict__ base,
                             const int* __restrict__ offGB, int2* __restrict__ stage,
                             int nnz, int B, int chunk) {
  __shared__ int cur[BMAX];
  int g = blockIdx.x;
  for (int i = threadIdx.x; i < B; i += blockDim.x)
    cur[i] = base[i] + offGB[(size_t)i * G_BLOCKS + g];
  __syncthreads();
  int s = g * chunk, e = min(nnz, s + chunk);
  for (int j = s + threadIdx.x; j < e; j += blockDim.x) {
    int r = row[j];
    int b = r >> RSH;
    int pos = atomicAdd(&cur[b], 1);   // LDS atomic
    int2 p;
    p.x = ((r & (RPB - 1)) << 24) | col[j];
    p.y = __float_as_int(val[j]);
    stage[pos] = p;
  }
}

// ---------------- phase B': partition each bucket's edges by col-group --------
// hist -> serial scan (thread 0, <=128 iters) -> scatter with LDS cursors.

__global__ void bp_k(const int2* __restrict__ stage, const int* __restrict__ base,
                     int2* __restrict__ edges, int CG) {
  __shared__ int h[CGMAX];
  int b = blockIdx.x, t = threadIdx.x;
  for (int i = t; i < CG; i += 256) h[i] = 0;
  __syncthreads();
  int s = base[b], e = base[b + 1];
  for (int j = s + t; j < e; j += 256)
    atomicAdd(&h[(stage[j].x & 0xFFFFFF) >> CSH], 1);
  __syncthreads();
  if (t == 0) {
    int run = s;
    for (int i = 0; i < CG; ++i) { int c = h[i]; h[i] = run; run += c; }
  }
  __syncthreads();
  for (int j = s + t; j < e; j += 256) {
    int2 p = stage[j];
    int pos = atomicAdd(&h[(p.x & 0xFFFFFF) >> CSH], 1);  // LDS cursor
    edges[pos] = p;
  }
}

// ---------------- blocked SpMM: one block per 128-row bucket, LDS out tile ----
// Edges arrive col-ascending; all resident blocks sweep the col space in phase,
// so the device-wide active x window stays small (L2/L3-resident).

__global__ __launch_bounds__(256) void
spmm_b_k(const int* __restrict__ base, const int2* __restrict__ edges,
         const float* __restrict__ x, float* __restrict__ y, int n) {
  __shared__ float tile[RPB * DHID];
  int b = blockIdx.x, t = threadIdx.x, lane = t & 63, w = t >> 6;
  float4 z4 = {0.f, 0.f, 0.f, 0.f};
  for (int i = t; i < RPB * DHID / 4; i += 256) ((float4*)tile)[i] = z4;
  __syncthreads();
  int s = __builtin_amdgcn_readfirstlane(base[b]);
  int e = __builtin_amdgcn_readfirstlane(base[b + 1]);
  for (int k0 = s + w * 8; k0 < e; k0 += 32) {
    if (k0 + 8 <= e) {
      int2 e0 = edges[k0 + 0], e1 = edges[k0 + 1], e2 = edges[k0 + 2], e3 = edges[k0 + 3];
      int2 e4 = edges[k0 + 4], e5 = edges[k0 + 5], e6 = edges[k0 + 6], e7 = edges[k0 + 7];
      float x0 = x[((size_t)(e0.x & 0xFFFFFF) << 6) + lane];
      float x1 = x[((size_t)(e1.x & 0xFFFFFF) << 6) + lane];
      float x2 = x[((size_t)(e2.x & 0xFFFFFF) << 6) + lane];
      float x3 = x[((size_t)(e3.x & 0xFFFFFF) << 6) + lane];
      float x4 = x[((size_t)(e4.x & 0xFFFFFF) << 6) + lane];
      float x5 = x[((size_t)(e5.x & 0xFFFFFF) << 6) + lane];
      float x6 = x[((size_t)(e6.x & 0xFFFFFF) << 6) + lane];
      float x7 = x[((size_t)(e7.x & 0xFFFFFF) << 6) + lane];
      atomicAdd(&tile[((((unsigned)e0.x) >> 24) << 6) + lane], __int_as_float(e0.y) * x0);
      atomicAdd(&tile[((((unsigned)e1.x) >> 24) << 6) + lane], __int_as_float(e1.y) * x1);
      atomicAdd(&tile[((((unsigned)e2.x) >> 24) << 6) + lane], __int_as_float(e2.y) * x2);
      atomicAdd(&tile[((((unsigned)e3.x) >> 24) << 6) + lane], __int_as_float(e3.y) * x3);
      atomicAdd(&tile[((((unsigned)e4.x) >> 24) << 6) + lane], __int_as_float(e4.y) * x4);
      atomicAdd(&tile[((((unsigned)e5.x) >> 24) << 6) + lane], __int_as_float(e5.y) * x5);
      atomicAdd(&tile[((((unsigned)e6.x) >> 24) << 6) + lane], __int_as_float(e6.y) * x6);
      atomicAdd(&tile[((((unsigned)e7.x) >> 24) << 6) + lane], __int_as_float(e7.y) * x7);
    } else {
      for (int k = k0; k < e; ++k) {
        int2 p = edges[k];
        float xv = x[((size_t)(p.x & 0xFFFFFF) << 6) + lane];
        atomicAdd(&tile[((((unsigned)p.x) >> 24) << 6) + lane], __int_as_float(p.y) * xv);
      }
    }
  }
  __syncthreads();
  int rowbase = b << RSH;
  for (int i = t; i < RPB * DHID / 4; i += 256) {
    int gr = rowbase + (i >> 4);
    if (gr < n) ((float4*)y)[((size_t)gr << 4) + (i & 15)] = ((float4*)tile)[i];
  }
}

// layer-2 blocked SpMM with fused epilogue (e2, summed, e0 copy)
__global__ __launch_bounds__(256) void
spmm_b_fused_k(const int* __restrict__ base, const int2* __restrict__ edges,
               const float* __restrict__ e0, const float* __restrict__ e1,
               float* __restrict__ e2, float* __restrict__ summed,
               float* __restrict__ e0out, int n) {
  __shared__ float tile[RPB * DHID];
  int b = blockIdx.x, t = threadIdx.x, lane = t & 63, w = t >> 6;
  float4 z4 = {0.f, 0.f, 0.f, 0.f};
  for (int i = t; i < RPB * DHID / 4; i += 256) ((float4*)tile)[i] = z4;
  __syncthreads();
  int s = __builtin_amdgcn_readfirstlane(base[b]);
  int e = __builtin_amdgcn_readfirstlane(base[b + 1]);
  for (int k0 = s + w * 8; k0 < e; k0 += 32) {
    if (k0 + 8 <= e) {
      int2 q0 = edges[k0 + 0], q1 = edges[k0 + 1], q2 = edges[k0 + 2], q3 = edges[k0 + 3];
      int2 q4 = edges[k0 + 4], q5 = edges[k0 + 5], q6 = edges[k0 + 6], q7 = edges[k0 + 7];
      float x0 = e1[((size_t)(q0.x & 0xFFFFFF) << 6) + lane];
      float x1 = e1[((size_t)(q1.x & 0xFFFFFF) << 6) + lane];
      float x2 = e1[((size_t)(q2.x & 0xFFFFFF) << 6) + lane];
      float x3 = e1[((size_t)(q3.x & 0xFFFFFF) << 6) + lane];
      float x4 = e1[((size_t)(q4.x & 0xFFFFFF) << 6) + lane];
      float x5 = e1[((size_t)(q5.x & 0xFFFFFF) << 6) + lane];
      float x6 = e1[((size_t)(q6.x & 0xFFFFFF) << 6) + lane];
      float x7 = e1[((size_t)(q7.x & 0xFFFFFF) << 6) + lane];
      atomicAdd(&tile[((((unsigned)q0.x) >> 24) << 6) + lane], __int_as_float(q0.y) * x0);
      atomicAdd(&tile[((((unsigned)q1.x) >> 24) << 6) + lane], __int_as_float(q1.y) * x1);
      atomicAdd(&tile[((((unsigned)q2.x) >> 24) << 6) + lane], __int_as_float(q2.y) * x2);
      atomicAdd(&tile[((((unsigned)q3.x) >> 24) << 6) + lane], __int_as_float(q3.y) * x3);
      atomicAdd(&tile[((((unsigned)q4.x) >> 24) << 6) + lane], __int_as_float(q4.y) * x4);
      atomicAdd(&tile[((((unsigned)q5.x) >> 24) << 6) + lane], __int_as_float(q5.y) * x5);
      atomicAdd(&tile[((((unsigned)q6.x) >> 24) << 6) + lane], __int_as_float(q6.y) * x6);
      atomicAdd(&tile[((((unsigned)q7.x) >> 24) << 6) + lane], __int_as_float(q7.y) * x7);
    } else {
      for (int k = k0; k < e; ++k) {
        int2 p = edges[k];
        float xv = e1[((size_t)(p.x & 0xFFFFFF) << 6) + lane];
        atomicAdd(&tile[((((unsigned)p.x) >> 24) << 6) + lane], __int_as_float(p.y) * xv);
      }
    }
  }
  __syncthreads();
  int rowbase = b << RSH;
  for (int i = t; i < RPB * DHID / 4; i += 256) {
    int gr = rowbase + (i >> 4);
    if (gr < n) {
      size_t o = ((size_t)gr << 4) + (i & 15);
      float4 acc = ((float4*)tile)[i];
      float4 v0 = ((const float4*)e0)[o];
      float4 v1 = ((const float4*)e1)[o];
      float4 sm;
      sm.x = v0.x + v1.x + acc.x;
      sm.y = v0.y + v1.y + acc.y;
      sm.z = v0.z + v1.z + acc.z;
      sm.w = v0.w + v1.w + acc.w;
      ((float4*)e2)[o] = acc;
      ((float4*)summed)[o] = sm;
      ((float4*)e0out)[o] = v0;
    }
  }
}

// ---------------- fallback: atomic path ----------------

__global__ void spmm_atomic_k(const int* __restrict__ row, const int* __restrict__ col,
                              const float* __restrict__ val, const float* __restrict__ x,
                              float* __restrict__ y, int nnz) {
  int wave = (blockIdx.x * blockDim.x + threadIdx.x) >> 6;
  int lane = threadIdx.x & 63;
  if (wave >= nnz) return;
  int r = row[wave]; int c = col[wave]; float v = val[wave];
  atomicAdd(&y[(size_t)r * DHID + lane], v * x[(size_t)c * DHID + lane]);
}

__global__ void sum_k(const float4* __restrict__ e0, const float4* __restrict__ e1,
                      const float4* __restrict__ e2, float4* __restrict__ summed,
                      float4* __restrict__ e0out, int n4) {
  int i = blockIdx.x * blockDim.x + threadIdx.x;
  if (i < n4) {
    float4 a = e0[i], b = e1[i], c = e2[i];
    float4 s;
    s.x = a.x + b.x + c.x;
    s.y = a.y + b.y + c.y;
    s.z = a.z + b.z + c.z;
    s.w = a.w + b.w + c.w;
    summed[i] = s;
    e0out[i] = a;
  }
}

extern "C" void kernel_launch(void* const* d_in, const int* in_sizes, int n_in,
                              void* d_out, int out_size, void* d_ws, size_t ws_size,
                              hipStream_t stream) {
  const int*   row = (const int*)d_in[0];
  const int*   col = (const int*)d_in[1];
  const float* val = (const float*)d_in[2];
  const float* emb = (const float*)d_in[3];
  int nnz = in_sizes[0];
  int n   = in_sizes[3] / DHID;
  size_t ND = (size_t)n * DHID;

  float* out    = (float*)d_out;
  float* summed = out;
  float* e0o    = out + ND;
  float* e1     = out + 2 * ND;
  float* e2     = out + 3 * ND;

  int B  = (n + RPB - 1) >> RSH;      // 128-row buckets
  int CG = (n + (1 << CSH) - 1) >> CSH;
  int chunk = (nnz + G_BLOCKS - 1) / G_BLOCKS;

  // carve workspace
  size_t o0 = 0;
  size_t histGB_off = o0; o0 += align256((size_t)BMAX * G_BLOCKS * 4);
  size_t offGB_off  = o0; o0 += align256((size_t)BMAX * G_BLOCKS * 4);
  size_t btot_off   = o0; o0 += align256((size_t)BMAX * 4);
  size_t base_off   = o0; o0 += align256((size_t)(BMAX + 1) * 4);
  size_t stage_off  = o0; o0 += align256((size_t)nnz * 8);
  size_t edges_off  = o0; o0 += align256((size_t)nnz * 8);
  size_t need = o0;

  bool use_sorted = (ws_size >= need) && (B <= BMAX) && (CG <= CGMAX) &&
                    (n < (1 << 24));

  int n4 = (int)(ND / 4);
  int sb = (n4 + 255) / 256;
  int wb = (int)(((size_t)nnz * 64 + 255) / 256);

  if (use_sorted) {
    uint8_t* w = (uint8_t*)d_ws;
    int*  histGB = (int*)(w + histGB_off);
    int*  offGB  = (int*)(w + offGB_off);
    int*  btot   = (int*)(w + btot_off);
    int*  base   = (int*)(w + base_off);
    int2* stage  = (int2*)(w + stage_off);
    int2* edges  = (int2*)(w + edges_off);

    // phase A: partition into 128-row buckets, zero global atomics
    a1_hist_k<<<G_BLOCKS, 256, 0, stream>>>(row, histGB, nnz, B, chunk);
    scan_gb_k<<<B, 256, 0, stream>>>(histGB, offGB, btot, B);
    scan_b_k<<<1, 256, 0, stream>>>(btot, base, B);
    a2_scatter_k<<<G_BLOCKS, 256, 0, stream>>>(row, col, val, base, offGB, stage,
                                               nnz, B, chunk);
    // phase B': col-group edges within each bucket (in-phase col sweep for spmm)
    bp_k<<<B, 256, 0, stream>>>(stage, base, edges, CG);

    // blocked SpMM x2 (layer 2 fuses the e0+e1+e2 epilogue)
    spmm_b_k<<<B, 256, 0, stream>>>(base, edges, emb, e1, n);
    spmm_b_fused_k<<<B, 256, 0, stream>>>(base, edges, emb, e1, e2, summed, e0o, n);
  } else {
    zero_f32<<<(int)((ND + 255) / 256), 256, 0, stream>>>(e1, ND);
    spmm_atomic_k<<<wb, 256, 0, stream>>>(row, col, val, emb, e1, nnz);
    zero_f32<<<(int)((ND + 255) / 256), 256, 0, stream>>>(e2, ND);
    spmm_atomic_k<<<wb, 256, 0, stream>>>(row, col, val, e1, e2, nnz);
    sum_k<<<sb, 256, 0, stream>>>((const float4*)emb, (const float4*)e1,
                                  (const float4*)e2, (float4*)summed,
                                  (float4*)e0o, n4);
  }
}